// Round 1
// baseline (478.703 us; speedup 1.0000x reference)
//
#include <hip/hip_runtime.h>
#include <math.h>

#define NUM_T   1000
#define NUM_R   8
#define NUM_AT  192
#define NO      64
#define NH      128
#define NBINS   200
#define FPB     5                         // frames per block
#define PAIRS_PER_FRAME (64*64 + 128*128 + 128*64)   // 28672

// ---------------------------------------------------------------------------
// Kernel 1: accumulate integer histograms per (replica, pair-type, bin).
// Bit-exact replication of the reference fp32 arithmetic:
//   x  = (r/L - floor(r/L)) * L          (== r/L % 1.0 * L for r,L >= 0)
//   dx = |x0-x1|; if dx > 0.5*L: dx -= L
//   d  = sqrtf((dx*dx + dy*dy) + dz*dz)   (no FMA contraction!)
//   bin = searchsorted(bins, d, 'right') - 1, clipped to [0,199]
//   count iff d != 0 && d >= bins[0] && d <= 10.0f
// bins = float32(np.linspace(1e-6, 10, 201)) computed in f64 then cast.
// ---------------------------------------------------------------------------
__global__ __launch_bounds__(256) void rdf_hist_kernel(
    const float* __restrict__ radii,      // [T][R][192][3]
    const float* __restrict__ lat,        // [3]
    unsigned int* __restrict__ gh)        // [R][3][200]
{
    #pragma clang fp contract(off)
    __shared__ float px[NUM_AT], py[NUM_AT], pz[NUM_AT];
    __shared__ unsigned int hist[3*NBINS];
    __shared__ float bins[NBINS+1];

    const int tid   = threadIdx.x;
    const int rep   = blockIdx.x % NUM_R;
    const int chunk = blockIdx.x / NUM_R;

    for (int i = tid; i <= NBINS; i += 256) {
        const double step = (10.0 - 1e-6) / 200.0;
        bins[i] = (i == NBINS) ? 10.0f : (float)(1e-6 + (double)i * step);
    }
    for (int i = tid; i < 3*NBINS; i += 256) hist[i] = 0u;

    const float Lx = lat[0], Ly = lat[1], Lz = lat[2];
    const float hxl = 0.5f*Lx, hyl = 0.5f*Ly, hzl = 0.5f*Lz;
    __syncthreads();

    for (int f = 0; f < FPB; ++f) {
        const int t = chunk * FPB + f;
        const float* src = radii + ((size_t)t*NUM_R + rep) * (NUM_AT*3);
        for (int i = tid; i < NUM_AT; i += 256) {
            float vx = src[i*3+0], vy = src[i*3+1], vz = src[i*3+2];
            float ux = vx / Lx; ux -= floorf(ux);
            float uy = vy / Ly; uy -= floorf(uy);
            float uz = vz / Lz; uz -= floorf(uz);
            px[i] = ux*Lx; py[i] = uy*Ly; pz[i] = uz*Lz;
        }
        __syncthreads();

        for (int slot = tid; slot < PAIRS_PER_FRAME; slot += 256) {
            int p, i, j;
            if (slot < 4096)       { p = 0; i =  slot >> 6;              j =  slot & 63; }
            else if (slot < 20480) { int s = slot - 4096;  p = 1; i = (s >> 7) + NO; j = (s & 127) + NO; }
            else                   { int s = slot - 20480; p = 2; i = (s >> 6) + NO; j =  s & 63; }

            float dx = fabsf(px[i] - px[j]); if (dx > hxl) dx = dx - Lx;
            float dy = fabsf(py[i] - py[j]); if (dy > hyl) dy = dy - Ly;
            float dz = fabsf(pz[i] - pz[j]); if (dz > hzl) dz = dz - Lz;
            float d  = sqrtf((dx*dx + dy*dy) + dz*dz);

            if (d != 0.0f && d >= bins[0] && d <= 10.0f) {
                int k = (int)(d * 20.0f);                 // close initial guess
                if (k > NBINS-1) k = NBINS-1;
                if (k < 0) k = 0;
                while (k < NBINS-1 && d >= bins[k+1]) ++k; // exact searchsorted fixup
                while (k > 0      && d <  bins[k])   --k;
                atomicAdd(&hist[p*NBINS + k], 1u);
            }
        }
        __syncthreads();
    }

    for (int i = tid; i < 3*NBINS; i += 256)
        atomicAdd(&gh[rep*3*NBINS + i], hist[i]);
}

// ---------------------------------------------------------------------------
// Kernel 2: g(r) = hist / (rho * shell); maes; max over pair types.
// ---------------------------------------------------------------------------
__global__ __launch_bounds__(256) void rdf_final_kernel(
    const unsigned int* __restrict__ gh,  // [R][3][200]
    const float* __restrict__ gt,         // [3][200]
    const float* __restrict__ lat,        // [3]
    float* __restrict__ out)              // [R][600] then [R] maxmae
{
    #pragma clang fp contract(off)
    const int rep = blockIdx.x;
    const int tid = threadIdx.x;
    __shared__ float bins[NBINS+1];
    __shared__ float red[256];

    for (int i = tid; i <= NBINS; i += 256) {
        const double step = (10.0 - 1e-6) / 200.0;
        bins[i] = (i == NBINS) ? 10.0f : (float)(1e-6 + (double)i * step);
    }
    __syncthreads();

    const float vol = (lat[0]*lat[1])*lat[2];
    const float C   = 4.18879020478639053f;   // float(4/3*pi)
    const int npairs[3] = { NUM_T*NO*NO, NUM_T*NH*NH, NUM_T*NH*NO };

    float maxmae = -3.0e38f;                  // only tid 0's copy matters
    for (int p = 0; p < 3; ++p) {
        float diff = 0.0f;
        if (tid < NBINS) {
            float b0 = bins[tid], b1 = bins[tid+1];
            float shell = C * (b1*b1*b1 - b0*b0*b0);
            float rho = (float)npairs[p] / vol;
            float g = (float)gh[(rep*3 + p)*NBINS + tid] / (rho * shell);
            out[rep*3*NBINS + p*NBINS + tid] = g;
            diff = fabsf(g - gt[p*NBINS + tid]);
        }
        red[tid] = diff;
        __syncthreads();
        for (int s = 128; s > 0; s >>= 1) {
            if (tid < s) red[tid] += red[tid + s];
            __syncthreads();
        }
        if (tid == 0) {
            float mae = 10.0f * (red[0] / 200.0f);   // XLIM * mean
            if (mae > maxmae) maxmae = mae;
        }
        __syncthreads();
    }
    if (tid == 0) out[NUM_R*3*NBINS + rep] = maxmae;
}

// ---------------------------------------------------------------------------
extern "C" void kernel_launch(void* const* d_in, const int* in_sizes, int n_in,
                              void* d_out, int out_size, void* d_ws, size_t ws_size,
                              hipStream_t stream) {
    const float* radii = (const float*)d_in[0];
    const float* lat   = (const float*)d_in[1];
    const float* gt    = (const float*)d_in[2];
    unsigned int* gh   = (unsigned int*)d_ws;

    hipMemsetAsync(gh, 0, NUM_R*3*NBINS*sizeof(unsigned int), stream);

    dim3 grid(NUM_R * (NUM_T / FPB));     // 8 * 200 = 1600 blocks
    hipLaunchKernelGGL(rdf_hist_kernel, grid, dim3(256), 0, stream,
                       radii, lat, gh);
    hipLaunchKernelGGL(rdf_final_kernel, dim3(NUM_R), dim3(256), 0, stream,
                       gh, gt, lat, (float*)d_out);
}

// Round 2
// 206.198 us; speedup vs baseline: 2.3216x; 2.3216x over previous
//
#include <hip/hip_runtime.h>
#include <math.h>

#define NUM_T   1000
#define NUM_R   8
#define NUM_AT  192
#define NO      64
#define NH      128
#define NBINS   200
#define FPB     2                      // frames per block -> grid 8*500=4000
#define HSTRIDE 608                    // 600 + 8 pad: shifts banks by 8 per copy
#define NCOPY   4                      // histogram sub-copies by 16-lane group

__device__ __forceinline__ float approx_sqrt(float x) {
#if defined(__has_builtin)
#if __has_builtin(__builtin_amdgcn_sqrtf)
    return __builtin_amdgcn_sqrtf(x);
#else
    float r; asm("v_sqrt_f32 %0, %1" : "=v"(r) : "v"(x)); return r;
#endif
#else
    float r; asm("v_sqrt_f32 %0, %1" : "=v"(r) : "v"(x)); return r;
#endif
}

// ---------------------------------------------------------------------------
// Histogram kernel. Bit-exact vs numpy reference:
//  - wrap: u=v/L; u-=floor(u); x=u*L                     (same as before)
//  - min-image squared: a=min(|t|, L-|t|)  ; a^2 == ref delta^2 bitwise
//    (L-|t| is the exact negation of |t|-L; tie at |t|==L/2 gives equal vals)
//  - s=(ax*ax+ay*ay)+az*az with FMA contraction OFF == ref sum order
//  - binning on s vs thresholds T[k]=min{s: sqrtf(s)>=bins[k]} (exact, since
//    sqrtf is correctly rounded & monotone). Count iff T[0]<=s<T[201] where
//    T[201] uses nextafter(10,inf) (== d<=10). d!=0 subsumed by d>=1e-6.
//  - guess bin via 1-ulp v_sqrt_f32, branchless +-1 fixup (error << bin width)
// ---------------------------------------------------------------------------
__global__ __launch_bounds__(256) void rdf_hist_kernel(
    const float* __restrict__ radii,      // [T][R][192][3]
    const float* __restrict__ lat,        // [3]
    unsigned int* __restrict__ gh)        // [R][3][200]
{
    #pragma clang fp contract(off)
    __shared__ float4 pos[NUM_AT];                 // wrapped positions
    __shared__ float TT[NBINS + 2];                // T[0..200], T[201]=upper
    __shared__ unsigned int hist[NCOPY * HSTRIDE];

    const int tid   = threadIdx.x;
    const int rep   = blockIdx.x % NUM_R;
    const int chunk = blockIdx.x / NUM_R;

    // --- exact bin thresholds in squared space (once per block) ---
    if (tid < NBINS + 2) {
        float b;
        if (tid <= NBINS) {
            const double step = (10.0 - 1e-6) / 200.0;
            b = (tid == NBINS) ? 10.0f : (float)(1e-6 + (double)tid * step);
        } else {
            b = __uint_as_float(__float_as_uint(10.0f) + 1u); // nextafter(10,+inf)
        }
        unsigned lo = 0u, hi = 0x7F800000u;        // predicate true at +inf
        while (lo < hi) {
            unsigned mid = (lo + hi) >> 1;
            if (sqrtf(__uint_as_float(mid)) >= b) hi = mid; else lo = mid + 1;
        }
        TT[tid] = __uint_as_float(lo);
    }
    for (int i = tid; i < NCOPY * HSTRIDE; i += 256) hist[i] = 0u;

    const float Lx = lat[0], Ly = lat[1], Lz = lat[2];
    __syncthreads();

    const float T0 = TT[0];
    const float Tp = TT[NBINS + 1];
    const int   hc = (tid >> 4) & (NCOPY - 1);     // 16-lane-group copy

#define PAIR_BODY(pi, pj, hbase)                                          \
    {                                                                     \
        float tx = (pi).x - (pj).x;                                       \
        float ty = (pi).y - (pj).y;                                       \
        float tz = (pi).z - (pj).z;                                       \
        float ax = fminf(fabsf(tx), Lx - fabsf(tx));                      \
        float ay = fminf(fabsf(ty), Ly - fabsf(ty));                      \
        float az = fminf(fabsf(tz), Lz - fabsf(tz));                      \
        float s  = (ax*ax + ay*ay) + az*az;                               \
        if (s >= T0 && s < Tp) {                                          \
            int k0 = (int)(approx_sqrt(s) * 20.0f);                       \
            k0 = min(max(k0, 0), NBINS - 1);                              \
            float tlo = TT[k0], thi = TT[k0 + 1];                         \
            int k = k0 + (s >= thi ? 1 : 0) - (s < tlo ? 1 : 0);          \
            k = min(k, NBINS - 1);                                        \
            atomicAdd(&hist[(hbase) + k], 1u);                            \
        }                                                                 \
    }

    for (int f = 0; f < FPB; ++f) {
        const int t = chunk * FPB + f;
        const float* src = radii + ((size_t)t * NUM_R + rep) * (NUM_AT * 3);
        __syncthreads();                            // pos reuse barrier
        for (int i = tid; i < NUM_AT; i += 256) {
            float vx = src[i*3+0], vy = src[i*3+1], vz = src[i*3+2];
            float ux = vx / Lx; ux -= floorf(ux);
            float uy = vy / Ly; uy -= floorf(uy);
            float uz = vz / Lz; uz -= floorf(uz);
            pos[i] = make_float4(ux*Lx, uy*Ly, uz*Lz, 0.0f);
        }
        __syncthreads();

        // ---- O-O: i = tid&63, j in quarter (tid>>6); wave-uniform j ----
        {
            const int i = tid & 63, q = tid >> 6;
            const float4 pi = pos[i];
            const int hb = hc * HSTRIDE + 0 * NBINS;
            #pragma unroll 4
            for (int jj = 0; jj < 16; ++jj) {
                const float4 pj = pos[q * 16 + jj];
                PAIR_BODY(pi, pj, hb);
            }
        }
        // ---- H-H: i = 64+(tid&127), j in half (tid>>7) ----
        {
            const int i = 64 + (tid & 127), h = tid >> 7;
            const float4 pi = pos[i];
            const int hb = hc * HSTRIDE + 1 * NBINS;
            #pragma unroll 4
            for (int jj = 0; jj < 64; ++jj) {
                const float4 pj = pos[64 + h * 64 + jj];
                PAIR_BODY(pi, pj, hb);
            }
        }
        // ---- H-O: i(H) = 64+(tid&127), j(O) in half (tid>>7) ----
        {
            const int i = 64 + (tid & 127), h = tid >> 7;
            const float4 pi = pos[i];
            const int hb = hc * HSTRIDE + 2 * NBINS;
            #pragma unroll 4
            for (int jj = 0; jj < 32; ++jj) {
                const float4 pj = pos[h * 32 + jj];
                PAIR_BODY(pi, pj, hb);
            }
        }
    }
#undef PAIR_BODY

    __syncthreads();
    for (int i = tid; i < 3 * NBINS; i += 256) {
        unsigned int v = hist[i] + hist[HSTRIDE + i]
                       + hist[2*HSTRIDE + i] + hist[3*HSTRIDE + i];
        if (v) atomicAdd(&gh[rep * 3 * NBINS + i], v);
    }
}

// ---------------------------------------------------------------------------
// Finalize: g(r) = hist / (rho*shell); per-type MAE vs gt; max over types.
// ---------------------------------------------------------------------------
__global__ __launch_bounds__(256) void rdf_final_kernel(
    const unsigned int* __restrict__ gh,  // [R][3][200]
    const float* __restrict__ gt,         // [3][200]
    const float* __restrict__ lat,        // [3]
    float* __restrict__ out)              // [R][600] then [R] maxmae
{
    #pragma clang fp contract(off)
    const int rep = blockIdx.x;
    const int tid = threadIdx.x;
    __shared__ float bins[NBINS + 1];
    __shared__ float red[256];

    for (int i = tid; i <= NBINS; i += 256) {
        const double step = (10.0 - 1e-6) / 200.0;
        bins[i] = (i == NBINS) ? 10.0f : (float)(1e-6 + (double)i * step);
    }
    __syncthreads();

    const float vol = (lat[0] * lat[1]) * lat[2];
    const float C   = 4.18879020478639053f;   // float(4/3*pi)
    const int npairs[3] = { NUM_T*NO*NO, NUM_T*NH*NH, NUM_T*NH*NO };

    float maxmae = -3.0e38f;
    for (int p = 0; p < 3; ++p) {
        float diff = 0.0f;
        if (tid < NBINS) {
            float b0 = bins[tid], b1 = bins[tid + 1];
            float shell = C * (b1*b1*b1 - b0*b0*b0);
            float rho = (float)npairs[p] / vol;
            float g = (float)gh[(rep*3 + p)*NBINS + tid] / (rho * shell);
            out[rep*3*NBINS + p*NBINS + tid] = g;
            diff = fabsf(g - gt[p*NBINS + tid]);
        }
        red[tid] = diff;
        __syncthreads();
        for (int s = 128; s > 0; s >>= 1) {
            if (tid < s) red[tid] += red[tid + s];
            __syncthreads();
        }
        if (tid == 0) {
            float mae = 10.0f * (red[0] / 200.0f);
            if (mae > maxmae) maxmae = mae;
        }
        __syncthreads();
    }
    if (tid == 0) out[NUM_R*3*NBINS + rep] = maxmae;
}

// ---------------------------------------------------------------------------
extern "C" void kernel_launch(void* const* d_in, const int* in_sizes, int n_in,
                              void* d_out, int out_size, void* d_ws, size_t ws_size,
                              hipStream_t stream) {
    const float* radii = (const float*)d_in[0];
    const float* lat   = (const float*)d_in[1];
    const float* gt    = (const float*)d_in[2];
    unsigned int* gh   = (unsigned int*)d_ws;

    hipMemsetAsync(gh, 0, NUM_R * 3 * NBINS * sizeof(unsigned int), stream);

    dim3 grid(NUM_R * (NUM_T / FPB));     // 8 * 500 = 4000 blocks
    hipLaunchKernelGGL(rdf_hist_kernel, grid, dim3(256), 0, stream,
                       radii, lat, gh);
    hipLaunchKernelGGL(rdf_final_kernel, dim3(NUM_R), dim3(256), 0, stream,
                       gh, gt, lat, (float*)d_out);
}

// Round 3
// 122.058 us; speedup vs baseline: 3.9219x; 1.6893x over previous
//
#include <hip/hip_runtime.h>
#include <math.h>

#define NUM_T   1000
#define NUM_R   8
#define NUM_AT  192
#define NO      64
#define NH      128
#define NBINS   200
#define FPB     2                      // frames per block -> grid 8*500=4000
#define HSTRIDE 608                    // 600 + 8 pad: shifts banks by 8 per copy
#define NCOPY   4                      // histogram sub-copies by 16-lane group

__device__ __forceinline__ float approx_sqrt(float x) {
#if defined(__has_builtin)
#if __has_builtin(__builtin_amdgcn_sqrtf)
    return __builtin_amdgcn_sqrtf(x);
#else
    float r; asm("v_sqrt_f32 %0, %1" : "=v"(r) : "v"(x)); return r;
#endif
#else
    float r; asm("v_sqrt_f32 %0, %1" : "=v"(r) : "v"(x)); return r;
#endif
}

// ---------------------------------------------------------------------------
// Bit-exact binning on squared distances (validated R1, absmax 3.9e-3):
//   thresholds T[k] = min{s : sqrtf(s) >= bins[k]} (sqrtf correctly rounded,
//   monotone). Count iff T[0] <= s < Tp where Tp = thresh(nextafter(10,inf)).
//   Bin: k0 = trunc(approx_sqrt(400 s) - 0.0078125)  [one-sided guess,
//   error <= 3.5e-5 bins << bias, bias < 1 bin => k0 in {k-1, k}], then
//   k = k0 + (s >= TT[k0+1]); TT[200] = +inf makes the d==10 right-clip free.
// Symmetry: reference counts ordered pairs; OO/HH are symmetric, so we
//   enumerate unordered pairs once: j = (i + k) mod n, k = 1..n/2 (k = n/2
//   only for i < n/2), and add weight 2. HO is ordered, weight 1.
// ---------------------------------------------------------------------------
__global__ __launch_bounds__(256) void rdf_hist_kernel(
    const float* __restrict__ radii,      // [T][R][192][3]
    const float* __restrict__ lat,        // [3]
    unsigned int* __restrict__ gh)        // [R][3][200]
{
    #pragma clang fp contract(off)
    __shared__ float4 pos[NUM_AT];
    __shared__ float TT[NBINS + 2];                // T[0..199], [200]=inf, [201]=Tp
    __shared__ unsigned int hist[NCOPY * HSTRIDE];

    const int tid   = threadIdx.x;
    const int rep   = blockIdx.x % NUM_R;
    const int chunk = blockIdx.x / NUM_R;

    if (tid < NBINS + 2) {
        if (tid == NBINS) {
            TT[tid] = __uint_as_float(0x7F800000u);          // +inf
        } else {
            float b;
            if (tid < NBINS) {
                const double step = (10.0 - 1e-6) / 200.0;
                b = (float)(1e-6 + (double)tid * step);
            } else {
                b = __uint_as_float(__float_as_uint(10.0f) + 1u); // nextafter(10,+inf)
            }
            unsigned lo = 0u, hi = 0x7F800000u;
            while (lo < hi) {
                unsigned mid = (lo + hi) >> 1;
                if (sqrtf(__uint_as_float(mid)) >= b) hi = mid; else lo = mid + 1;
            }
            TT[tid] = __uint_as_float(lo);
        }
    }
    for (int i = tid; i < NCOPY * HSTRIDE; i += 256) hist[i] = 0u;

    const float Lx = lat[0], Ly = lat[1], Lz = lat[2];
    __syncthreads();

    const float T0 = TT[0];
    const float Tp = TT[NBINS + 1];
    const int   hc = (tid >> 4) & (NCOPY - 1);

#define PAIR_BODY(pi, j, hb, wgt)                                         \
    {                                                                     \
        const float4 pj = pos[j];                                         \
        float tx = (pi).x - pj.x;                                         \
        float ty = (pi).y - pj.y;                                         \
        float tz = (pi).z - pj.z;                                         \
        float ax = fminf(fabsf(tx), Lx - fabsf(tx));                      \
        float ay = fminf(fabsf(ty), Ly - fabsf(ty));                      \
        float az = fminf(fabsf(tz), Lz - fabsf(tz));                      \
        float s  = (ax*ax + ay*ay) + az*az;                               \
        int k0 = (int)(approx_sqrt(s * 400.0f) - 0.0078125f);             \
        k0 = min(k0, NBINS - 1);                                          \
        float thi = TT[k0 + 1];                                           \
        int k = k0 + ((s >= thi) ? 1 : 0);                                \
        if (s >= T0 && s < Tp) atomicAdd(&hist[(hb) + k], (wgt));         \
    }

    for (int f = 0; f < FPB; ++f) {
        const int t = chunk * FPB + f;
        const float* src = radii + ((size_t)t * NUM_R + rep) * (NUM_AT * 3);
        __syncthreads();
        for (int i = tid; i < NUM_AT; i += 256) {
            float vx = src[i*3+0], vy = src[i*3+1], vz = src[i*3+2];
            float ux = vx / Lx; ux -= floorf(ux);
            float uy = vy / Ly; uy -= floorf(uy);
            float uz = vz / Lz; uz -= floorf(uz);
            pos[i] = make_float4(ux*Lx, uy*Ly, uz*Lz, 0.0f);
        }
        __syncthreads();

        // ---- O-O unordered: i = tid&63, 4 threads/atom (q = tid>>6),
        //      k = 4*it + q + 1 for it=0..7; k=32 (q=3,it=7) half-coverage ----
        {
            const int i = tid & 63, q = tid >> 6;
            const float4 pi = pos[i];
            const int hb = hc * HSTRIDE + 0 * NBINS;
            const int jb = i + q + 1;
            #pragma unroll 4
            for (int it = 0; it < 7; ++it) {
                const int j = (jb + 4*it) & 63;
                PAIR_BODY(pi, j, hb, 2u);
            }
            {   // it = 7: k = 29+q; k==32 only when q==3
                const int j = (jb + 28) & 63;
                if (q < 3 || i < 32) PAIR_BODY(pi, j, hb, 2u);
            }
        }
        // ---- H-H unordered: iL = tid&127, 2 threads/atom (q = tid>>7),
        //      k = 2*it + q + 1 for it=0..31; k=64 (q=1,it=31) half ----
        const int iL = tid & 127, qh = tid >> 7;
        const float4 ph = pos[64 + iL];
        {
            const int hb = hc * HSTRIDE + 1 * NBINS;
            const int jb = iL + qh + 1;
            #pragma unroll 4
            for (int it = 0; it < 31; ++it) {
                const int j = 64 + ((jb + 2*it) & 127);
                PAIR_BODY(ph, j, hb, 2u);
            }
            {   // it = 31: k = 63+q; k==64 only when q==1
                const int j = 64 + ((jb + 62) & 127);
                if (qh == 0 || iL < 64) PAIR_BODY(ph, j, hb, 2u);
            }
        }
        // ---- H-O ordered (weight 1): i = H(64+iL), j = O(32*q + jj) ----
        {
            const int hb = hc * HSTRIDE + 2 * NBINS;
            #pragma unroll 4
            for (int jj = 0; jj < 32; ++jj) {
                const int j = 32 * qh + jj;
                PAIR_BODY(ph, j, hb, 1u);
            }
        }
    }
#undef PAIR_BODY

    __syncthreads();
    for (int i = tid; i < 3 * NBINS; i += 256) {
        unsigned int v = hist[i] + hist[HSTRIDE + i]
                       + hist[2*HSTRIDE + i] + hist[3*HSTRIDE + i];
        if (v) atomicAdd(&gh[rep * 3 * NBINS + i], v);
    }
}

// ---------------------------------------------------------------------------
__global__ __launch_bounds__(256) void rdf_final_kernel(
    const unsigned int* __restrict__ gh,  // [R][3][200]
    const float* __restrict__ gt,         // [3][200]
    const float* __restrict__ lat,        // [3]
    float* __restrict__ out)              // [R][600] then [R] maxmae
{
    #pragma clang fp contract(off)
    const int rep = blockIdx.x;
    const int tid = threadIdx.x;
    __shared__ float bins[NBINS + 1];
    __shared__ float red[256];

    for (int i = tid; i <= NBINS; i += 256) {
        const double step = (10.0 - 1e-6) / 200.0;
        bins[i] = (i == NBINS) ? 10.0f : (float)(1e-6 + (double)i * step);
    }
    __syncthreads();

    const float vol = (lat[0] * lat[1]) * lat[2];
    const float C   = 4.18879020478639053f;   // float(4/3*pi)
    const int npairs[3] = { NUM_T*NO*NO, NUM_T*NH*NH, NUM_T*NH*NO };

    float maxmae = -3.0e38f;
    for (int p = 0; p < 3; ++p) {
        float diff = 0.0f;
        if (tid < NBINS) {
            float b0 = bins[tid], b1 = bins[tid + 1];
            float shell = C * (b1*b1*b1 - b0*b0*b0);
            float rho = (float)npairs[p] / vol;
            float g = (float)gh[(rep*3 + p)*NBINS + tid] / (rho * shell);
            out[rep*3*NBINS + p*NBINS + tid] = g;
            diff = fabsf(g - gt[p*NBINS + tid]);
        }
        red[tid] = diff;
        __syncthreads();
        for (int s = 128; s > 0; s >>= 1) {
            if (tid < s) red[tid] += red[tid + s];
            __syncthreads();
        }
        if (tid == 0) {
            float mae = 10.0f * (red[0] / 200.0f);
            if (mae > maxmae) maxmae = mae;
        }
        __syncthreads();
    }
    if (tid == 0) out[NUM_R*3*NBINS + rep] = maxmae;
}

// ---------------------------------------------------------------------------
extern "C" void kernel_launch(void* const* d_in, const int* in_sizes, int n_in,
                              void* d_out, int out_size, void* d_ws, size_t ws_size,
                              hipStream_t stream) {
    const float* radii = (const float*)d_in[0];
    const float* lat   = (const float*)d_in[1];
    const float* gt    = (const float*)d_in[2];
    unsigned int* gh   = (unsigned int*)d_ws;

    hipMemsetAsync(gh, 0, NUM_R * 3 * NBINS * sizeof(unsigned int), stream);

    dim3 grid(NUM_R * (NUM_T / FPB));     // 8 * 500 = 4000 blocks
    hipLaunchKernelGGL(rdf_hist_kernel, grid, dim3(256), 0, stream,
                       radii, lat, gh);
    hipLaunchKernelGGL(rdf_final_kernel, dim3(NUM_R), dim3(256), 0, stream,
                       gh, gt, lat, (float*)d_out);
}

// Round 4
// 109.658 us; speedup vs baseline: 4.3654x; 1.1131x over previous
//
#include <hip/hip_runtime.h>
#include <math.h>

#define NUM_T   1000
#define NUM_R   8
#define NBINS   200
#define FPB     4                       // frames per block -> grid 8*250=2000
#define NCOPY   8                       // hist copies, one per 8-lane group
#define HSTR    601                     // words/copy; 601%32=25 -> bank shift
#define TTSZ    224                     // padded threshold table

__device__ __forceinline__ float approx_sqrt(float x) {
    float r; asm("v_sqrt_f32 %0, %1" : "=v"(r) : "v"(x)); return r;
}
__device__ __forceinline__ float fract_(float x) {
#if __has_builtin(__builtin_amdgcn_fractf)
    return __builtin_amdgcn_fractf(x);
#else
    return x - floorf(x);
#endif
}

// ---------------------------------------------------------------------------
// Bit-exact binning on squared distances (validated R1-R3):
//   TT[k] = min{s : sqrtf(s) >= bins[k]}  (sqrtf correctly rounded, monotone)
//   TT[200] = Tp = min{s : sqrtf(s) > 10}; count iff s < Tp (d<=10).
//   Fast path: z = v_sqrt(400*s). Boundary-image analysis: image of TT[k]
//   lies in k + 2e-5 +- 8e-5 (fl(400s) 2^-24, v_sqrt <=1ulp monotone, bins
//   table <=1.3e-5 bins). If frac(z) outside +-2e-4 of integer: k=(int)z
//   exact. Else (~4e-4 of pairs): slow path resolves via TT reads. Exact.
// Pair enumeration (symmetric types counted once, weight 2):
//   OO:   rotation (i, i+k) k=1..32 over 64 atoms (k=32 half), dup'd posOx
//   HH:   diag(H0) + diag(H1) rotations + H0 x H1 cross with wave-uniform j
//   HO:   ordered, weight 1, wave-uniform j (LDS broadcast)
// ---------------------------------------------------------------------------
__global__ __launch_bounds__(256) void rdf_hist_kernel(
    const float* __restrict__ radii,      // [T][R][192][3]
    const float* __restrict__ lat,        // [3]
    unsigned int* __restrict__ gh)        // [R][3][200]
{
    #pragma clang fp contract(off)
    __shared__ float4 posOx[96], posH0[96], posH1[96];
    __shared__ float TT[TTSZ];
    __shared__ unsigned int hist[NCOPY * HSTR];

    const int tid = threadIdx.x;

    // thresholds: TT[0..199] bin lower edges (squared space), TT[200]=Tp,
    // TT[201..] = +inf padding (slow-path reads of discarded pairs).
    if (tid < TTSZ) {
        float v;
        if (tid <= 200) {
            float b;
            if (tid < NBINS) {
                const double step = (10.0 - 1e-6) / 200.0;
                b = (float)(1e-6 + (double)tid * step);
            } else {
                b = __uint_as_float(__float_as_uint(10.0f) + 1u); // nextafter(10,inf)
            }
            unsigned lo = 0u, hi = 0x7F800000u;
            while (lo < hi) {
                unsigned mid = (lo + hi) >> 1;
                if (sqrtf(__uint_as_float(mid)) >= b) hi = mid; else lo = mid + 1;
            }
            v = __uint_as_float(lo);
        } else {
            v = __uint_as_float(0x7F800000u);
        }
        TT[tid] = v;
    }
    for (int i = tid; i < NCOPY * HSTR; i += 256) hist[i] = 0u;

    const float Lx = lat[0], Ly = lat[1], Lz = lat[2];
    __syncthreads();

    const float Tp = TT[200];
    const int   hc = ((tid >> 3) & (NCOPY - 1)) * HSTR;

#define PAIR(PI, PJ, HB, W)                                                  \
    {                                                                        \
        float tx = (PI).x - (PJ).x;                                          \
        float ty = (PI).y - (PJ).y;                                          \
        float tz = (PI).z - (PJ).z;                                          \
        float ax = fminf(fabsf(tx), Lx - fabsf(tx));                         \
        float ay = fminf(fabsf(ty), Ly - fabsf(ty));                         \
        float az = fminf(fabsf(tz), Lz - fabsf(tz));                         \
        float s  = (ax*ax + ay*ay) + az*az;                                  \
        float z  = approx_sqrt(s * 400.0f);                                  \
        int   k  = (int)z;                                                   \
        float m  = fract_(z);                                                \
        if (__builtin_expect(fabsf(m - 0.5f) > 0.49980f, 0)) {               \
            float tlo = TT[k], thi = TT[k + 1];                              \
            k += ((s >= thi) ? 1 : 0) - ((s < tlo) ? 1 : 0);                 \
            k = max(k, 0);                                                   \
        }                                                                    \
        if (s < Tp) atomicAdd(&hist[(HB) + k], (W));                         \
    }

    const int rep   = blockIdx.x & (NUM_R - 1);
    const int chunk = blockIdx.x / NUM_R;
    const int iO = tid & 63;          // atom-in-tile
    const int q  = tid >> 6;          // wave id 0..3 (wave-uniform)
    const int hO = tid & 127;         // H atom for HO
    const int qh = tid >> 7;          // 0..1 (wave-uniform)

    for (int f = 0; f < FPB; ++f) {
        const int t = chunk * FPB + f;
        const float* src = radii + ((size_t)t * NUM_R + rep) * (192 * 3);
        __syncthreads();
        if (tid < 192) {
            float vx = src[tid*3+0], vy = src[tid*3+1], vz = src[tid*3+2];
            float ux = vx / Lx; ux -= floorf(ux);
            float uy = vy / Ly; uy -= floorf(uy);
            float uz = vz / Lz; uz -= floorf(uz);
            float4 p = make_float4(ux*Lx, uy*Ly, uz*Lz, 0.0f);
            if (tid < 64)       { posOx[tid] = p;        if (tid < 32)  posOx[tid+64] = p; }
            else if (tid < 128) { int h = tid-64;  posH0[h] = p; if (h < 32) posH0[h+64] = p; }
            else                { int h = tid-128; posH1[h] = p; if (h < 32) posH1[h+64] = p; }
        }
        __syncthreads();

        // ---- O-O rotation: k = q+1+4*it; k=32 (q=3,it=7) half-covered ----
        {
            const float4 pi = posOx[iO];
            const int hb = hc + 0 * NBINS;
            const int jb = iO + q + 1;
            #pragma unroll
            for (int it = 0; it < 7; ++it) { float4 pj = posOx[jb + 4*it]; PAIR(pi, pj, hb, 2u); }
            if (q < 3 || iO < 32)          { float4 pj = posOx[jb + 28];   PAIR(pi, pj, hb, 2u); }
        }
        // ---- H0 diag rotation ----
        {
            const float4 pi = posH0[iO];
            const int hb = hc + 1 * NBINS;
            const int jb = iO + q + 1;
            #pragma unroll
            for (int it = 0; it < 7; ++it) { float4 pj = posH0[jb + 4*it]; PAIR(pi, pj, hb, 2u); }
            if (q < 3 || iO < 32)          { float4 pj = posH0[jb + 28];   PAIR(pi, pj, hb, 2u); }
        }
        // ---- H1 diag rotation ----
        {
            const float4 pi = posH1[iO];
            const int hb = hc + 1 * NBINS;
            const int jb = iO + q + 1;
            #pragma unroll
            for (int it = 0; it < 7; ++it) { float4 pj = posH1[jb + 4*it]; PAIR(pi, pj, hb, 2u); }
            if (q < 3 || iO < 32)          { float4 pj = posH1[jb + 28];   PAIR(pi, pj, hb, 2u); }
        }
        // ---- HH cross (H0 x H1), weight 2, wave-uniform j (broadcast) ----
        {
            const float4 pi = posH0[iO];
            const int hb = hc + 1 * NBINS;
            const int jb = q * 16;
            #pragma unroll
            for (int jj = 0; jj < 16; ++jj) { float4 pj = posH1[jb + jj]; PAIR(pi, pj, hb, 2u); }
        }
        // ---- H-O ordered, weight 1, wave-uniform j (broadcast) ----
        {
            const float4 pi = (hO < 64) ? posH0[hO] : posH1[hO - 64];
            const int hb = hc + 2 * NBINS;
            const int jb = qh * 32;
            #pragma unroll
            for (int jj = 0; jj < 32; ++jj) { float4 pj = posOx[jb + jj]; PAIR(pi, pj, hb, 1u); }
        }
    }
#undef PAIR

    __syncthreads();
    for (int i = tid; i < 3 * NBINS; i += 256) {
        unsigned int v = 0;
        #pragma unroll
        for (int c = 0; c < NCOPY; ++c) v += hist[c * HSTR + i];
        if (v) atomicAdd(&gh[rep * 3 * NBINS + i], v);
    }
}

// ---------------------------------------------------------------------------
__global__ __launch_bounds__(256) void rdf_final_kernel(
    const unsigned int* __restrict__ gh,  // [R][3][200]
    const float* __restrict__ gt,         // [3][200]
    const float* __restrict__ lat,        // [3]
    float* __restrict__ out)              // [R][600] then [R] maxmae
{
    #pragma clang fp contract(off)
    const int rep = blockIdx.x;
    const int tid = threadIdx.x;
    __shared__ float bins[NBINS + 1];
    __shared__ float red[256];

    for (int i = tid; i <= NBINS; i += 256) {
        const double step = (10.0 - 1e-6) / 200.0;
        bins[i] = (i == NBINS) ? 10.0f : (float)(1e-6 + (double)i * step);
    }
    __syncthreads();

    const float vol = (lat[0] * lat[1]) * lat[2];
    const float C   = 4.18879020478639053f;   // float(4/3*pi)
    const int npairs[3] = { NUM_T*64*64, NUM_T*128*128, NUM_T*128*64 };

    float maxmae = -3.0e38f;
    for (int p = 0; p < 3; ++p) {
        float diff = 0.0f;
        if (tid < NBINS) {
            float b0 = bins[tid], b1 = bins[tid + 1];
            float shell = C * (b1*b1*b1 - b0*b0*b0);
            float rho = (float)npairs[p] / vol;
            float g = (float)gh[(rep*3 + p)*NBINS + tid] / (rho * shell);
            out[rep*3*NBINS + p*NBINS + tid] = g;
            diff = fabsf(g - gt[p*NBINS + tid]);
        }
        red[tid] = diff;
        __syncthreads();
        for (int s = 128; s > 0; s >>= 1) {
            if (tid < s) red[tid] += red[tid + s];
            __syncthreads();
        }
        if (tid == 0) {
            float mae = 10.0f * (red[0] / 200.0f);
            if (mae > maxmae) maxmae = mae;
        }
        __syncthreads();
    }
    if (tid == 0) out[NUM_R*3*NBINS + rep] = maxmae;
}

// ---------------------------------------------------------------------------
extern "C" void kernel_launch(void* const* d_in, const int* in_sizes, int n_in,
                              void* d_out, int out_size, void* d_ws, size_t ws_size,
                              hipStream_t stream) {
    const float* radii = (const float*)d_in[0];
    const float* lat   = (const float*)d_in[1];
    const float* gt    = (const float*)d_in[2];
    unsigned int* gh   = (unsigned int*)d_ws;

    hipMemsetAsync(gh, 0, NUM_R * 3 * NBINS * sizeof(unsigned int), stream);

    dim3 grid(NUM_R * (NUM_T / FPB));     // 8 * 250 = 2000 blocks
    hipLaunchKernelGGL(rdf_hist_kernel, grid, dim3(256), 0, stream,
                       radii, lat, gh);
    hipLaunchKernelGGL(rdf_final_kernel, dim3(NUM_R), dim3(256), 0, stream,
                       gh, gt, lat, (float*)d_out);
}

// Round 5
// 106.740 us; speedup vs baseline: 4.4848x; 1.0273x over previous
//
#include <hip/hip_runtime.h>
#include <math.h>

#define NUM_T   1000
#define NUM_R   8
#define NBINS   200
#define FPB     2                       // frames per block -> grid 8*500=4000
#define NCOPY   8                       // hist copies, one per 8-lane group
#define HSTR    601                     // words/copy; word 600 = dump slot
#define TTSZ    224                     // padded threshold table

__device__ __forceinline__ float approx_sqrt(float x) {
    float r; asm("v_sqrt_f32 %0, %1" : "=v"(r) : "v"(x)); return r;
}
__device__ __forceinline__ float fract_(float x) {
#if __has_builtin(__builtin_amdgcn_fractf)
    return __builtin_amdgcn_fractf(x);
#else
    return x - floorf(x);
#endif
}

// ---------------------------------------------------------------------------
// Bit-exact binning on squared distances (validated R1-R3, absmax 3.906e-3):
//   TT[k] = min{s : sqrtf(s) >= bins[k]}; TT[200] = Tp = min{s: sqrtf(s)>10}.
//   In-range test: bits(TT[0]) <= bits(s) < bits(Tp)  (positive floats are
//   bit-monotone; s=+0 (d==0) is excluded exactly like the reference mask).
//   Out-of-range pairs route to the copy's dump slot (word 600) -> atomic is
//   unconditional, no exec-mask dance.
//   Fast path k=(int)v_sqrt(400s) exact unless frac within +-2e-4 of integer
//   (boundary-image analysis R3); ambiguous -> whole-wave-vote slow path that
//   applies TT[k]/TT[k+1] corrections to ALL lanes (no-op for exact lanes).
// Pair enumeration (symmetric types once, weight 2):
//   OO/H0H0/H1H1: rotation (l, l+k), k=q+1+4*it, k=32 half-covered; dup'd pos
//   HH cross (H0 x H1): wave-uniform j, weight 2
//   HO: lane holds H0[l],H1[l] in regs; wave-uniform O read feeds 2 pairs, w1
// ---------------------------------------------------------------------------
__global__ __launch_bounds__(256) void rdf_hist_kernel(
    const float* __restrict__ radii,      // [T][R][192][3]
    const float* __restrict__ lat,        // [3]
    unsigned int* __restrict__ gh)        // [R][3][200]
{
    #pragma clang fp contract(off)
    __shared__ float4 posOx[96], posH0[96], posH1[96];
    __shared__ float TT[TTSZ];
    __shared__ unsigned int hist[NCOPY * HSTR];

    const int tid = threadIdx.x;

    if (tid < TTSZ) {
        float v;
        if (tid <= 200) {
            float b;
            if (tid < NBINS) {
                const double step = (10.0 - 1e-6) / 200.0;
                b = (float)(1e-6 + (double)tid * step);
            } else {
                b = __uint_as_float(__float_as_uint(10.0f) + 1u); // nextafter(10,inf)
            }
            unsigned lo = 0u, hi = 0x7F800000u;
            while (lo < hi) {
                unsigned mid = (lo + hi) >> 1;
                if (sqrtf(__uint_as_float(mid)) >= b) hi = mid; else lo = mid + 1;
            }
            v = __uint_as_float(lo);
        } else {
            v = __uint_as_float(0x7F800000u);
        }
        TT[tid] = v;
    }
    for (int i = tid; i < NCOPY * HSTR; i += 256) hist[i] = 0u;

    const float Lx = lat[0], Ly = lat[1], Lz = lat[2];
    __syncthreads();

    const unsigned T0b = __float_as_uint(TT[0]);
    const unsigned Rng = __float_as_uint(TT[200]) - T0b;   // [T0, Tp) width
    const int      hc  = ((tid >> 3) & (NCOPY - 1)) * HSTR;

#define PAIR(PI, PJ, TOFF, W)                                                \
    {                                                                        \
        float tx = (PI).x - (PJ).x;                                          \
        float ty = (PI).y - (PJ).y;                                          \
        float tz = (PI).z - (PJ).z;                                          \
        float ax = fminf(fabsf(tx), Lx - fabsf(tx));                         \
        float ay = fminf(fabsf(ty), Ly - fabsf(ty));                         \
        float az = fminf(fabsf(tz), Lz - fabsf(tz));                         \
        float s  = (ax*ax + ay*ay) + az*az;                                  \
        float z  = approx_sqrt(s * 400.0f);                                  \
        int   k  = (int)z;                                                   \
        float m  = fract_(z);                                                \
        bool amb = fabsf(m - 0.5f) > 0.49980f;                               \
        if (__builtin_expect(__any(amb), 0)) {                               \
            float tlo = TT[k], thi = TT[k + 1];                              \
            k += ((s >= thi) ? 1 : 0) - ((s < tlo) ? 1 : 0);                 \
        }                                                                    \
        bool inr = (__float_as_uint(s) - T0b) < Rng;                         \
        int  kk  = inr ? ((TOFF) + k) : 600;                                 \
        atomicAdd(&hist[hc + kk], (W));                                      \
    }

    const int rep   = blockIdx.x & (NUM_R - 1);
    const int chunk = blockIdx.x / NUM_R;
    const int l     = tid & 63;
    const int q     = tid >> 6;          // wave id 0..3 (wave-uniform)

    // prefetch frame 0 raw coords
    float rvx = 0.f, rvy = 0.f, rvz = 0.f;
    {
        const float* s0 = radii + ((size_t)(chunk * FPB) * NUM_R + rep) * (192 * 3);
        if (tid < 192) { rvx = s0[tid*3+0]; rvy = s0[tid*3+1]; rvz = s0[tid*3+2]; }
    }

    #pragma unroll 1
    for (int f = 0; f < FPB; ++f) {
        __syncthreads();
        if (tid < 192) {
            float ux = rvx / Lx; ux -= floorf(ux);
            float uy = rvy / Ly; uy -= floorf(uy);
            float uz = rvz / Lz; uz -= floorf(uz);
            float4 p = make_float4(ux*Lx, uy*Ly, uz*Lz, 0.0f);
            if (tid < 64)       { posOx[tid] = p;  if (tid < 32) posOx[tid+64] = p; }
            else if (tid < 128) { int h = tid-64;  posH0[h] = p; if (h < 32) posH0[h+64] = p; }
            else                { int h = tid-128; posH1[h] = p; if (h < 32) posH1[h+64] = p; }
        }
        __syncthreads();

        if (f + 1 < FPB && tid < 192) {   // prefetch next frame during compute
            const float* s1 = radii + ((size_t)(chunk * FPB + f + 1) * NUM_R + rep) * (192 * 3);
            rvx = s1[tid*3+0]; rvy = s1[tid*3+1]; rvz = s1[tid*3+2];
        }

        const float4 piO = posOx[l];
        const float4 pi0 = posH0[l];
        const float4 pi1 = posH1[l];
        const int jb = l + q + 1;

        // ---- O-O rotation: k = q+1+4*it; k=32 (q=3,it=7) half-covered ----
        #pragma unroll
        for (int it = 0; it < 7; ++it) { float4 pj = posOx[jb + 4*it]; PAIR(piO, pj, 0, 2u); }
        if (q < 3 || l < 32)           { float4 pj = posOx[jb + 28];   PAIR(piO, pj, 0, 2u); }

        // ---- H0 diag rotation ----
        #pragma unroll
        for (int it = 0; it < 7; ++it) { float4 pj = posH0[jb + 4*it]; PAIR(pi0, pj, 200, 2u); }
        if (q < 3 || l < 32)           { float4 pj = posH0[jb + 28];   PAIR(pi0, pj, 200, 2u); }

        // ---- H1 diag rotation ----
        #pragma unroll
        for (int it = 0; it < 7; ++it) { float4 pj = posH1[jb + 4*it]; PAIR(pi1, pj, 200, 2u); }
        if (q < 3 || l < 32)           { float4 pj = posH1[jb + 28];   PAIR(pi1, pj, 200, 2u); }

        // ---- HH cross (H0 x H1), weight 2, wave-uniform j ----
        #pragma unroll 4
        for (int jj = 0; jj < 16; ++jj) {
            float4 pj = posH1[q * 16 + jj];
            PAIR(pi0, pj, 200, 2u);
        }
        // ---- H-O ordered, weight 1: one uniform O read feeds both H rows ----
        #pragma unroll 4
        for (int jj = 0; jj < 16; ++jj) {
            float4 pj = posOx[q * 16 + jj];
            PAIR(pi0, pj, 400, 1u);
            PAIR(pi1, pj, 400, 1u);
        }
    }
#undef PAIR

    __syncthreads();
    for (int i = tid; i < 3 * NBINS; i += 256) {
        unsigned int v = 0;
        #pragma unroll
        for (int c = 0; c < NCOPY; ++c) v += hist[c * HSTR + i];
        if (v) atomicAdd(&gh[rep * 3 * NBINS + i], v);
    }
}

// ---------------------------------------------------------------------------
__global__ __launch_bounds__(256) void rdf_final_kernel(
    const unsigned int* __restrict__ gh,  // [R][3][200]
    const float* __restrict__ gt,         // [3][200]
    const float* __restrict__ lat,        // [3]
    float* __restrict__ out)              // [R][600] then [R] maxmae
{
    #pragma clang fp contract(off)
    const int rep = blockIdx.x;
    const int tid = threadIdx.x;
    __shared__ float bins[NBINS + 1];
    __shared__ float red[256];

    for (int i = tid; i <= NBINS; i += 256) {
        const double step = (10.0 - 1e-6) / 200.0;
        bins[i] = (i == NBINS) ? 10.0f : (float)(1e-6 + (double)i * step);
    }
    __syncthreads();

    const float vol = (lat[0] * lat[1]) * lat[2];
    const float C   = 4.18879020478639053f;   // float(4/3*pi)
    const int npairs[3] = { NUM_T*64*64, NUM_T*128*128, NUM_T*128*64 };

    float maxmae = -3.0e38f;
    for (int p = 0; p < 3; ++p) {
        float diff = 0.0f;
        if (tid < NBINS) {
            float b0 = bins[tid], b1 = bins[tid + 1];
            float shell = C * (b1*b1*b1 - b0*b0*b0);
            float rho = (float)npairs[p] / vol;
            float g = (float)gh[(rep*3 + p)*NBINS + tid] / (rho * shell);
            out[rep*3*NBINS + p*NBINS + tid] = g;
            diff = fabsf(g - gt[p*NBINS + tid]);
        }
        red[tid] = diff;
        __syncthreads();
        for (int s = 128; s > 0; s >>= 1) {
            if (tid < s) red[tid] += red[tid + s];
            __syncthreads();
        }
        if (tid == 0) {
            float mae = 10.0f * (red[0] / 200.0f);
            if (mae > maxmae) maxmae = mae;
        }
        __syncthreads();
    }
    if (tid == 0) out[NUM_R*3*NBINS + rep] = maxmae;
}

// ---------------------------------------------------------------------------
extern "C" void kernel_launch(void* const* d_in, const int* in_sizes, int n_in,
                              void* d_out, int out_size, void* d_ws, size_t ws_size,
                              hipStream_t stream) {
    const float* radii = (const float*)d_in[0];
    const float* lat   = (const float*)d_in[1];
    const float* gt    = (const float*)d_in[2];
    unsigned int* gh   = (unsigned int*)d_ws;

    hipMemsetAsync(gh, 0, NUM_R * 3 * NBINS * sizeof(unsigned int), stream);

    dim3 grid(NUM_R * (NUM_T / FPB));     // 8 * 500 = 4000 blocks
    hipLaunchKernelGGL(rdf_hist_kernel, grid, dim3(256), 0, stream,
                       radii, lat, gh);
    hipLaunchKernelGGL(rdf_final_kernel, dim3(NUM_R), dim3(256), 0, stream,
                       gh, gt, lat, (float*)d_out);
}